// Round 1
// baseline (111.338 us; speedup 1.0000x reference)
//
#include <hip/hip_runtime.h>
#include <hip/hip_bf16.h>

// B=128, V=1024, D=512.
// 2 kernels:
//   gemm_prep: blocks [0,176) three bf16 MFMA GEMMs, BK=64, LDS double-buffered
//              (one barrier/iter), f32 loaded + cvt in-reg:
//                fp    = feat @ Wf^T              (128x512 f32, b-major for s_load)
//                ppbT  = Wp @ proto^T + b1        (512x1024 bf16, k-major)
//                dotraw= feat @ proto^T           (128x1024 f32)
//              blocks [176,192) zipf ranks -> zw ; blocks [192,480) row inv-norms
//   fused:     one block per b (128 blocks x 1024 thr). Thread (vp, kh) accumulates
//              sum_{k in half} relu(fp[b][k]+ppbT[k][v])*W2[k] for a v-pair,
//              LDS-reduce the two k-halves, then combine + softmax in-place.
//              Eliminates the 16x128x1024 f32 hsp round-trip (16.8 MB) and one launch.

typedef __attribute__((ext_vector_type(8))) short bhalf8;
typedef __attribute__((ext_vector_type(4))) float f32x4;

static __device__ __forceinline__ unsigned short f2bf(float x) {
    union { __hip_bfloat16 h; unsigned short u; } cv;
    cv.h = __float2bfloat16(x);
    return cv.u;
}

static __device__ __forceinline__ int4 pack_bf16_8(float4 x, float4 y) {
    union { ushort u[8]; int4 v; } r;
    r.u[0] = f2bf(x.x); r.u[1] = f2bf(x.y); r.u[2] = f2bf(x.z); r.u[3] = f2bf(x.w);
    r.u[4] = f2bf(y.x); r.u[5] = f2bf(y.y); r.u[6] = f2bf(y.z); r.u[7] = f2bf(y.w);
    return r.v;
}

// ---------------- gemm_prep ----------------
__global__ __launch_bounds__(256) void gemm_prep_kernel(
    const float* __restrict__ feat, const float* __restrict__ counts,
    const float* __restrict__ proto, const float* __restrict__ zs,
    const float* __restrict__ W1, const float* __restrict__ b1,
    float* __restrict__ fp, unsigned short* __restrict__ ppbT,
    float* __restrict__ dotraw,
    float* __restrict__ zw, float* __restrict__ invf, float* __restrict__ invp)
{
    int bx = blockIdx.x, tid = threadIdx.x;

    if (bx >= 176) {
        if (bx < 192) {
            // zipf: 64 i's per block; 4 threads per i scan quarters of j
            __shared__ float cn[1024];
            ((float4*)cn)[tid] = ((const float4*)counts)[tid];
            __syncthreads();
            int il = tid >> 2, q = tid & 3;
            int i = (bx - 176) * 64 + il;
            float ci = cn[i];
            int cnt = 0;
            int j0 = q * 256;
            for (int j = j0; j < j0 + 256; ++j) {
                float cj = cn[j];
                cnt += (cj > ci) ? 1 : 0;
                cnt += (cj == ci && j < i) ? 1 : 0;  // stable tie-break
            }
            cnt += __shfl_xor(cnt, 1);
            cnt += __shfl_xor(cnt, 2);
            if (q == 0) zw[i] = powf((float)(cnt + 1), -zs[0]);
        } else {
            // inverse L2 norms: 4 rows/block, 1 wave/row
            int nb = bx - 192;
            int w = tid >> 6, lane = tid & 63;
            int row = nb * 4 + w;
            const float* src = (row < 128) ? (feat + (size_t)row * 512)
                                           : (proto + (size_t)(row - 128) * 512);
            const float4* rp = (const float4*)src;
            float4 a = rp[lane * 2], b = rp[lane * 2 + 1];
            float ss = a.x*a.x + a.y*a.y + a.z*a.z + a.w*a.w
                     + b.x*b.x + b.y*b.y + b.z*b.z + b.w*b.w;
            for (int o = 32; o; o >>= 1) ss += __shfl_xor(ss, o);
            if (lane == 0) {
                float inv = 1.0f / fmaxf(sqrtf(ss), 1e-12f);
                if (row < 128) invf[row] = inv; else invp[row - 128] = inv;
            }
        }
        return;
    }

    // ---- GEMM: 64x64 tiles, BK=64, double-buffered LDS, one barrier/iter ----
    const float* A; const float* Bm;
    int lda, ldb, tm, tn, mode;  // 0: fp (f32 b-major), 1: ppbT (bf16+bias), 2: dotraw
    if (bx < 16) {
        A = feat; lda = 512; Bm = W1; ldb = 1024; mode = 0;
        tm = bx >> 3; tn = bx & 7;
    } else if (bx < 144) {
        int t = bx - 16;
        A = W1 + 512; lda = 1024; Bm = proto; ldb = 512; mode = 1;
        tm = t >> 4; tn = t & 15;
    } else {
        int t = bx - 144;
        A = feat; lda = 512; Bm = proto; ldb = 512; mode = 2;
        tm = t >> 4; tn = t & 15;
    }

    __shared__ unsigned short As[2][64 * 72];  // stride 72 halfs: 2-way alias max (free)
    __shared__ unsigned short Bs[2][64 * 72];

    int r = tid >> 2, kq = (tid & 3) * 16;   // row 0..63, k-offset {0,16,32,48} halfs
    int wave = tid >> 6, lane = tid & 63;
    int fr = lane & 15, quad = lane >> 4;

    const float* Ag = A + (size_t)(tm * 64 + r) * lda + kq;
    const float* Bg = Bm + (size_t)(tn * 64 + r) * ldb + kq;

    float4 a0 = *(const float4*)(Ag),      a1 = *(const float4*)(Ag + 4);
    float4 a2 = *(const float4*)(Ag + 8),  a3 = *(const float4*)(Ag + 12);
    float4 g0 = *(const float4*)(Bg),      g1 = *(const float4*)(Bg + 4);
    float4 g2 = *(const float4*)(Bg + 8),  g3 = *(const float4*)(Bg + 12);

    f32x4 acc0 = {0.f, 0.f, 0.f, 0.f};
    f32x4 acc1 = acc0, acc2 = acc0, acc3 = acc0;

    for (int kc = 0; kc < 512; kc += 64) {
        int p = (kc >> 6) & 1;
        *(int4*)&As[p][r * 72 + kq]     = pack_bf16_8(a0, a1);
        *(int4*)&As[p][r * 72 + kq + 8] = pack_bf16_8(a2, a3);
        *(int4*)&Bs[p][r * 72 + kq]     = pack_bf16_8(g0, g1);
        *(int4*)&Bs[p][r * 72 + kq + 8] = pack_bf16_8(g2, g3);
        __syncthreads();
        if (kc + 64 < 512) {  // prefetch next tile into regs; overlaps ds_read+MFMA
            const float* An = Ag + kc + 64;
            const float* Bn = Bg + kc + 64;
            a0 = *(const float4*)(An);     a1 = *(const float4*)(An + 4);
            a2 = *(const float4*)(An + 8); a3 = *(const float4*)(An + 12);
            g0 = *(const float4*)(Bn);     g1 = *(const float4*)(Bn + 4);
            g2 = *(const float4*)(Bn + 8); g3 = *(const float4*)(Bn + 12);
        }
        #pragma unroll
        for (int s = 0; s < 2; ++s) {
            int ko = s * 32 + quad * 8;
            bhalf8 af  = *(const bhalf8*)&As[p][(wave * 16 + fr) * 72 + ko];
            bhalf8 bf0 = *(const bhalf8*)&Bs[p][(fr) * 72 + ko];
            bhalf8 bf1 = *(const bhalf8*)&Bs[p][(16 + fr) * 72 + ko];
            bhalf8 bf2 = *(const bhalf8*)&Bs[p][(32 + fr) * 72 + ko];
            bhalf8 bf3 = *(const bhalf8*)&Bs[p][(48 + fr) * 72 + ko];
            acc0 = __builtin_amdgcn_mfma_f32_16x16x32_bf16(af, bf0, acc0, 0, 0, 0);
            acc1 = __builtin_amdgcn_mfma_f32_16x16x32_bf16(af, bf1, acc1, 0, 0, 0);
            acc2 = __builtin_amdgcn_mfma_f32_16x16x32_bf16(af, bf2, acc2, 0, 0, 0);
            acc3 = __builtin_amdgcn_mfma_f32_16x16x32_bf16(af, bf3, acc3, 0, 0, 0);
        }
        // NOTE: single barrier per iter is safe — a wave only rewrites buf[p]
        // two iters later, after passing the next barrier, by which time all
        // waves have consumed their ds_reads of buf[p] (waitcnt before MFMA).
    }

    // C/D layout: col = lane&15, row = quad*4 + reg  [m89/m91]
    int m0 = tm * 64 + wave * 16 + quad * 4;
    int n0 = tn * 64 + fr;
    f32x4 accs[4] = {acc0, acc1, acc2, acc3};
    if (mode == 0) {
        // fp[b][k], b-major: b = m0+rr, k = n0+j*16
        for (int j = 0; j < 4; ++j)
            for (int rr = 0; rr < 4; ++rr)
                fp[(size_t)(m0 + rr) * 512 + n0 + j * 16] = accs[j][rr];
    } else if (mode == 1) {
        float bv4[4];
        for (int rr = 0; rr < 4; ++rr) bv4[rr] = b1[m0 + rr];
        for (int j = 0; j < 4; ++j)
            for (int rr = 0; rr < 4; ++rr)
                ppbT[(size_t)(m0 + rr) * 1024 + n0 + j * 16] = f2bf(accs[j][rr] + bv4[rr]);
    } else {
        for (int j = 0; j < 4; ++j)
            for (int rr = 0; rr < 4; ++rr)
                dotraw[(size_t)(m0 + rr) * 1024 + n0 + j * 16] = accs[j][rr];
    }
}

// ---------------- fused hs + combine + softmax ----------------
// One block per b: 1024 thr. tid -> (vp = tid&511: v-pair, kh = tid>>9: k-half).
// Each thread accumulates 256 k's for 2 v's; halves reduced via LDS; then
// per-thread v = tid for combine + softmax (identical to old combine logic).
__global__ __launch_bounds__(1024) void fused_kernel(
    const float* __restrict__ fp, const unsigned short* __restrict__ ppbT,
    const float* __restrict__ W2,
    const float* __restrict__ dotraw, const float* __restrict__ zw,
    const float* __restrict__ invf, const float* __restrict__ invp,
    const float* __restrict__ temp, const float* __restrict__ b2,
    float* __restrict__ out)
{
    int b = blockIdx.x, tid = threadIdx.x;
    int vp = tid & 511, kh = tid >> 9;

    const float* fpb = fp + (size_t)b * 512 + kh * 256;   // uniform per wave -> s_load
    const float* w2b = W2 + kh * 256;                     // uniform -> s_load
    const unsigned short* pb = ppbT + (size_t)(kh * 256) * 1024 + vp * 2;

    // two accumulators per v (k-parity) to break the fma dependency chain
    float a0[2] = {0.f, 0.f}, a1[2] = {0.f, 0.f};
    #pragma unroll 8
    for (int kk = 0; kk < 256; ++kk) {
        unsigned int u = *(const unsigned int*)(pb + (size_t)kk * 1024);
        float px = __uint_as_float(u << 16);
        float py = __uint_as_float(u & 0xffff0000u);
        float w2k = w2b[kk];
        float fk  = fpb[kk];
        a0[kk & 1] += fmaxf(fk + px, 0.f) * w2k;
        a1[kk & 1] += fmaxf(fk + py, 0.f) * w2k;
    }

    __shared__ float hred[2][1024];
    *(float2*)&hred[kh][vp * 2] = make_float2(a0[0] + a0[1], a1[0] + a1[1]);
    __syncthreads();

    // ---- combine + softmax: thread owns v = tid ----
    int wave = tid >> 6, lane = tid & 63;
    int v = tid;
    __shared__ float red[16];

    float h   = hred[0][v] + hred[1][v];
    float it  = invf[b] / fmaxf(temp[0], 1e-4f);
    float b2v = b2[0];
    float zwv = zw[v];
    float dr  = dotraw[(size_t)b * 1024 + v];
    float ipv = invp[v];

    // zw-sum (recomputed locally; cheaper than an extra pass)
    float zs4 = zwv;
    for (int o = 32; o; o >>= 1) zs4 += __shfl_xor(zs4, o);
    if (lane == 0) red[wave] = zs4;
    __syncthreads();
    float zsum = 0.f;
    #pragma unroll
    for (int i = 0; i < 16; ++i) zsum += red[i];
    float izw = 1.0f / fmaxf(zsum, 1e-8f);
    __syncthreads();

    float sim = dr * it * ipv;
    float g = h + b2v;
    float w = (zwv * izw) * (1.0f + sim) * (1.0f / (1.0f + expf(-g)));

    float mx = w;
    for (int o = 32; o; o >>= 1) mx = fmaxf(mx, __shfl_xor(mx, o));
    if (lane == 0) red[wave] = mx;
    __syncthreads();
    mx = red[0];
    #pragma unroll
    for (int i = 1; i < 16; ++i) mx = fmaxf(mx, red[i]);
    __syncthreads();

    float e = expf(w - mx);
    float sm = e;
    for (int o = 32; o; o >>= 1) sm += __shfl_xor(sm, o);
    if (lane == 0) red[wave] = sm;
    __syncthreads();
    float tot = 0.f;
    #pragma unroll
    for (int i = 0; i < 16; ++i) tot += red[i];

    out[(size_t)b * 1024 + v] = e / tot;
}

// ---------------- launch ----------------
extern "C" void kernel_launch(void* const* d_in, const int* in_sizes, int n_in,
                              void* d_out, int out_size, void* d_ws, size_t ws_size,
                              hipStream_t stream) {
    const float* feat   = (const float*)d_in[0];
    const float* counts = (const float*)d_in[1];
    // d_in[2] total_count: ranks invariant under positive rescale -> unused
    const float* proto  = (const float*)d_in[3];
    const float* zs     = (const float*)d_in[4];
    const float* temp   = (const float*)d_in[5];
    const float* W1     = (const float*)d_in[6];
    const float* b1     = (const float*)d_in[7];
    const float* W2     = (const float*)d_in[8];
    const float* b2     = (const float*)d_in[9];

    char* ws = (char*)d_ws;
    float* zw     = (float*)(ws + 0);              // 1024 f32
    float* invf   = (float*)(ws + 4096);           // 128 f32
    float* invp   = (float*)(ws + 4608);           // 1024 f32
    float* fp     = (float*)(ws + 8704);           // 128x512 f32 (b-major)
    float* dotraw = (float*)(ws + 270848);         // 128x1024 f32
    unsigned short* ppbT = (unsigned short*)(ws + 795136);  // 512x1024 bf16

    gemm_prep_kernel<<<480, 256, 0, stream>>>(feat, counts, proto, zs, W1, b1,
                                              fp, ppbT, dotraw, zw, invf, invp);
    fused_kernel<<<128, 1024, 0, stream>>>(fp, ppbT, W2, dotraw, zw, invf, invp,
                                           temp, b2, (float*)d_out);
}

// Round 2
// 99.023 us; speedup vs baseline: 1.1244x; 1.1244x over previous
//
#include <hip/hip_runtime.h>
#include <hip/hip_bf16.h>

// B=128, V=1024, D=512.
// 3 kernels (revert of failed round-1 fusion: 128-block fused kernel halved GPU
// utilization for the heavy VALU phase and 4x'd ppbT L2 traffic; ksplit restored):
//   gemm_prep: blocks [0,176) three bf16 MFMA GEMMs, BK=64, LDS double-buffered
//              (one barrier/iter), f32 loaded + cvt in-reg:
//                fpT   = (feat @ Wf^T)^T          (512x128 f32, transposed for hs)
//                ppbT  = Wp @ proto^T + b1        (512x1024 bf16)
//                dotraw= feat @ proto^T           (128x1024 f32)
//              blocks [176,192) zipf ranks -> zw + per-block partial sums zwpart
//              blocks [192,480) row inv-norms
//   hs:        hs[ks][b][v] = sum_{k in seg64} relu(fpT[k][b]+ppbT[k][v])*W2[k]
//              b-tile 4, v-tile 512, ksplit 8 -> 512 blocks (2/CU, 8 waves/CU)
//              (ksplit 16->8: halves hsp traffic 8.4->4.2 MB, combine loads 16->8)
//   combine:   1024 thr/block, 1 v/thread; zsum from zwpart (scalar, no reduction);
//              w = (zw/zsum)*(1+sim)*sigmoid(.); softmax

typedef __attribute__((ext_vector_type(8))) short bhalf8;
typedef __attribute__((ext_vector_type(4))) float f32x4;

static __device__ __forceinline__ unsigned short f2bf(float x) {
    union { __hip_bfloat16 h; unsigned short u; } cv;
    cv.h = __float2bfloat16(x);
    return cv.u;
}

static __device__ __forceinline__ int4 pack_bf16_8(float4 x, float4 y) {
    union { ushort u[8]; int4 v; } r;
    r.u[0] = f2bf(x.x); r.u[1] = f2bf(x.y); r.u[2] = f2bf(x.z); r.u[3] = f2bf(x.w);
    r.u[4] = f2bf(y.x); r.u[5] = f2bf(y.y); r.u[6] = f2bf(y.z); r.u[7] = f2bf(y.w);
    return r.v;
}

// ---------------- gemm_prep ----------------
__global__ __launch_bounds__(256) void gemm_prep_kernel(
    const float* __restrict__ feat, const float* __restrict__ counts,
    const float* __restrict__ proto, const float* __restrict__ zs,
    const float* __restrict__ W1, const float* __restrict__ b1,
    float* __restrict__ fpT, unsigned short* __restrict__ ppbT,
    float* __restrict__ dotraw,
    float* __restrict__ zw, float* __restrict__ zwpart,
    float* __restrict__ invf, float* __restrict__ invp)
{
    int bx = blockIdx.x, tid = threadIdx.x;

    if (bx >= 176) {
        if (bx < 192) {
            // zipf: 64 i's per block; 4 threads per i scan quarters of j
            __shared__ float cn[1024];
            __shared__ float zr[4];
            ((float4*)cn)[tid] = ((const float4*)counts)[tid];
            __syncthreads();
            int il = tid >> 2, q = tid & 3;
            int i = (bx - 176) * 64 + il;
            float ci = cn[i];
            int cnt = 0;
            int j0 = q * 256;
            for (int j = j0; j < j0 + 256; ++j) {
                float cj = cn[j];
                cnt += (cj > ci) ? 1 : 0;
                cnt += (cj == ci && j < i) ? 1 : 0;  // stable tie-break
            }
            cnt += __shfl_xor(cnt, 1);
            cnt += __shfl_xor(cnt, 2);
            float zwv = 0.f;
            if (q == 0) {
                zwv = powf((float)(cnt + 1), -zs[0]);
                zw[i] = zwv;
            }
            // block partial sum of zw -> zwpart[bx-176] (combine sums 16 scalars)
            float ps = zwv;
            for (int o = 32; o; o >>= 1) ps += __shfl_xor(ps, o);
            int wv = tid >> 6, lane = tid & 63;
            if (lane == 0) zr[wv] = ps;
            __syncthreads();
            if (tid == 0) zwpart[bx - 176] = zr[0] + zr[1] + zr[2] + zr[3];
        } else {
            // inverse L2 norms: 4 rows/block, 1 wave/row
            int nb = bx - 192;
            int w = tid >> 6, lane = tid & 63;
            int row = nb * 4 + w;
            const float* src = (row < 128) ? (feat + (size_t)row * 512)
                                           : (proto + (size_t)(row - 128) * 512);
            const float4* rp = (const float4*)src;
            float4 a = rp[lane * 2], b = rp[lane * 2 + 1];
            float ss = a.x*a.x + a.y*a.y + a.z*a.z + a.w*a.w
                     + b.x*b.x + b.y*b.y + b.z*b.z + b.w*b.w;
            for (int o = 32; o; o >>= 1) ss += __shfl_xor(ss, o);
            if (lane == 0) {
                float inv = 1.0f / fmaxf(sqrtf(ss), 1e-12f);
                if (row < 128) invf[row] = inv; else invp[row - 128] = inv;
            }
        }
        return;
    }

    // ---- GEMM: 64x64 tiles, BK=64, double-buffered LDS, one barrier/iter ----
    const float* A; const float* Bm;
    int lda, ldb, tm, tn, mode;  // 0: fpT (f32 transposed), 1: ppbT (bf16+bias), 2: dotraw
    if (bx < 16) {
        A = feat; lda = 512; Bm = W1; ldb = 1024; mode = 0;
        tm = bx >> 3; tn = bx & 7;
    } else if (bx < 144) {
        int t = bx - 16;
        A = W1 + 512; lda = 1024; Bm = proto; ldb = 512; mode = 1;
        tm = t >> 4; tn = t & 15;
    } else {
        int t = bx - 144;
        A = feat; lda = 512; Bm = proto; ldb = 512; mode = 2;
        tm = t >> 4; tn = t & 15;
    }

    __shared__ unsigned short As[2][64 * 72];  // stride 72 halfs: 2-way alias max (free)
    __shared__ unsigned short Bs[2][64 * 72];

    int r = tid >> 2, kq = (tid & 3) * 16;   // row 0..63, k-offset {0,16,32,48} halfs
    int wave = tid >> 6, lane = tid & 63;
    int fr = lane & 15, quad = lane >> 4;

    const float* Ag = A + (size_t)(tm * 64 + r) * lda + kq;
    const float* Bg = Bm + (size_t)(tn * 64 + r) * ldb + kq;

    float4 a0 = *(const float4*)(Ag),      a1 = *(const float4*)(Ag + 4);
    float4 a2 = *(const float4*)(Ag + 8),  a3 = *(const float4*)(Ag + 12);
    float4 g0 = *(const float4*)(Bg),      g1 = *(const float4*)(Bg + 4);
    float4 g2 = *(const float4*)(Bg + 8),  g3 = *(const float4*)(Bg + 12);

    f32x4 acc0 = {0.f, 0.f, 0.f, 0.f};
    f32x4 acc1 = acc0, acc2 = acc0, acc3 = acc0;

    for (int kc = 0; kc < 512; kc += 64) {
        int p = (kc >> 6) & 1;
        *(int4*)&As[p][r * 72 + kq]     = pack_bf16_8(a0, a1);
        *(int4*)&As[p][r * 72 + kq + 8] = pack_bf16_8(a2, a3);
        *(int4*)&Bs[p][r * 72 + kq]     = pack_bf16_8(g0, g1);
        *(int4*)&Bs[p][r * 72 + kq + 8] = pack_bf16_8(g2, g3);
        __syncthreads();
        if (kc + 64 < 512) {  // prefetch next tile into regs; overlaps ds_read+MFMA
            const float* An = Ag + kc + 64;
            const float* Bn = Bg + kc + 64;
            a0 = *(const float4*)(An);     a1 = *(const float4*)(An + 4);
            a2 = *(const float4*)(An + 8); a3 = *(const float4*)(An + 12);
            g0 = *(const float4*)(Bn);     g1 = *(const float4*)(Bn + 4);
            g2 = *(const float4*)(Bn + 8); g3 = *(const float4*)(Bn + 12);
        }
        #pragma unroll
        for (int s = 0; s < 2; ++s) {
            int ko = s * 32 + quad * 8;
            bhalf8 af  = *(const bhalf8*)&As[p][(wave * 16 + fr) * 72 + ko];
            bhalf8 bf0 = *(const bhalf8*)&Bs[p][(fr) * 72 + ko];
            bhalf8 bf1 = *(const bhalf8*)&Bs[p][(16 + fr) * 72 + ko];
            bhalf8 bf2 = *(const bhalf8*)&Bs[p][(32 + fr) * 72 + ko];
            bhalf8 bf3 = *(const bhalf8*)&Bs[p][(48 + fr) * 72 + ko];
            acc0 = __builtin_amdgcn_mfma_f32_16x16x32_bf16(af, bf0, acc0, 0, 0, 0);
            acc1 = __builtin_amdgcn_mfma_f32_16x16x32_bf16(af, bf1, acc1, 0, 0, 0);
            acc2 = __builtin_amdgcn_mfma_f32_16x16x32_bf16(af, bf2, acc2, 0, 0, 0);
            acc3 = __builtin_amdgcn_mfma_f32_16x16x32_bf16(af, bf3, acc3, 0, 0, 0);
        }
        // NOTE: single barrier per iter is safe — a wave only rewrites buf[p]
        // two iters later, after passing the next barrier, by which time all
        // waves have consumed their ds_reads of buf[p] (waitcnt before MFMA).
    }

    // C/D layout: col = lane&15, row = quad*4 + reg  [m89/m91]
    int m0 = tm * 64 + wave * 16 + quad * 4;
    int n0 = tn * 64 + fr;
    f32x4 accs[4] = {acc0, acc1, acc2, acc3};
    if (mode == 0) {
        for (int j = 0; j < 4; ++j)
            for (int rr = 0; rr < 4; ++rr)
                fpT[(size_t)(n0 + j * 16) * 128 + m0 + rr] = accs[j][rr];
    } else if (mode == 1) {
        float bv4[4];
        for (int rr = 0; rr < 4; ++rr) bv4[rr] = b1[m0 + rr];
        for (int j = 0; j < 4; ++j)
            for (int rr = 0; rr < 4; ++rr)
                ppbT[(size_t)(m0 + rr) * 1024 + n0 + j * 16] = f2bf(accs[j][rr] + bv4[rr]);
    } else {
        for (int j = 0; j < 4; ++j)
            for (int rr = 0; rr < 4; ++rr)
                dotraw[(size_t)(m0 + rr) * 1024 + n0 + j * 16] = accs[j][rr];
    }
}

// ---------------- hs: partial[ks][b][v] = sum_{k in seg64} relu(fpT[k][b]+ppbT[k][v])*W2[k] ---
// grid 512 = bg(32, b-tile 4) x vh(2, v-tile 512) x ks(8, 64 k's); 256 thr, 2 v/thread
__global__ __launch_bounds__(256) void hs_kernel(
    const float* __restrict__ fpT, const unsigned short* __restrict__ ppbT,
    const float* __restrict__ W2, float* __restrict__ hsp)
{
    int bx = blockIdx.x, tid = threadIdx.x;
    int bg = bx & 31, vh = (bx >> 5) & 1, ks = bx >> 6;
    int b0 = bg * 4, v = vh * 512 + tid * 2, k0 = ks * 64;

    float acc[4][2] = {};
    #pragma unroll 8
    for (int kk = 0; kk < 64; ++kk) {
        int k = k0 + kk;
        unsigned int u = *(const unsigned int*)(ppbT + (size_t)k * 1024 + v);
        float px = __uint_as_float(u << 16);
        float py = __uint_as_float(u & 0xffff0000u);
        float w2k = W2[k];                                        // uniform -> s_load
        float4 fa = *(const float4*)(fpT + (size_t)k * 128 + b0); // uniform
        float f[4] = {fa.x, fa.y, fa.z, fa.w};
        #pragma unroll
        for (int i = 0; i < 4; ++i) {
            acc[i][0] += fmaxf(f[i] + px, 0.f) * w2k;
            acc[i][1] += fmaxf(f[i] + py, 0.f) * w2k;
        }
    }
    float* o = hsp + ((size_t)ks * 128 + b0) * 1024 + v;
    #pragma unroll
    for (int i = 0; i < 4; ++i)
        *(float2*)(o + (size_t)i * 1024) = make_float2(acc[i][0], acc[i][1]);
}

// ---------------- combine + softmax: one block per b, 1024 threads (1 v each) --------------
__global__ __launch_bounds__(1024) void combine_kernel(
    const float* __restrict__ dotraw, const float* __restrict__ hsp,
    const float* __restrict__ zw, const float* __restrict__ zwpart,
    const float* __restrict__ invf, const float* __restrict__ invp,
    const float* __restrict__ temp, const float* __restrict__ b2,
    float* __restrict__ out)
{
    int b = blockIdx.x, tid = threadIdx.x;
    int wave = tid >> 6, lane = tid & 63;
    int v = tid;
    __shared__ float red[16];

    float it  = invf[b] / fmaxf(temp[0], 1e-4f);
    float b2v = b2[0];

    float zwv = zw[v];
    float dr  = dotraw[(size_t)b * 1024 + v];
    float ipv = invp[v];

    float h = 0.f;
    #pragma unroll
    for (int s = 0; s < 8; ++s)
        h += hsp[((size_t)s * 128 + b) * 1024 + v];

    // zw-sum from gemm_prep's per-block partials: 16 uniform scalar loads
    float zsum = 0.f;
    #pragma unroll
    for (int i = 0; i < 16; ++i) zsum += zwpart[i];
    float izw = 1.0f / fmaxf(zsum, 1e-8f);

    float sim = dr * it * ipv;
    float g = h + b2v;
    float w = (zwv * izw) * (1.0f + sim) * (1.0f / (1.0f + expf(-g)));

    float mx = w;
    for (int o = 32; o; o >>= 1) mx = fmaxf(mx, __shfl_xor(mx, o));
    if (lane == 0) red[wave] = mx;
    __syncthreads();
    mx = red[0];
    #pragma unroll
    for (int i = 1; i < 16; ++i) mx = fmaxf(mx, red[i]);
    __syncthreads();

    float e = expf(w - mx);
    float sm = e;
    for (int o = 32; o; o >>= 1) sm += __shfl_xor(sm, o);
    if (lane == 0) red[wave] = sm;
    __syncthreads();
    float tot = 0.f;
    #pragma unroll
    for (int i = 0; i < 16; ++i) tot += red[i];

    out[(size_t)b * 1024 + v] = e / tot;
}

// ---------------- launch ----------------
extern "C" void kernel_launch(void* const* d_in, const int* in_sizes, int n_in,
                              void* d_out, int out_size, void* d_ws, size_t ws_size,
                              hipStream_t stream) {
    const float* feat   = (const float*)d_in[0];
    const float* counts = (const float*)d_in[1];
    // d_in[2] total_count: ranks invariant under positive rescale -> unused
    const float* proto  = (const float*)d_in[3];
    const float* zs     = (const float*)d_in[4];
    const float* temp   = (const float*)d_in[5];
    const float* W1     = (const float*)d_in[6];
    const float* b1     = (const float*)d_in[7];
    const float* W2     = (const float*)d_in[8];
    const float* b2     = (const float*)d_in[9];

    char* ws = (char*)d_ws;
    float* zw     = (float*)(ws + 0);              // 1024 f32
    float* zwpart = (float*)(ws + 4096);           // 16 f32
    float* invf   = (float*)(ws + 4224);           // 128 f32
    float* invp   = (float*)(ws + 4736);           // 1024 f32
    float* fpT    = (float*)(ws + 8832);           // 512x128 f32 (transposed fp)
    float* dotraw = (float*)(ws + 270976);         // 128x1024 f32
    unsigned short* ppbT = (unsigned short*)(ws + 795264);  // 512x1024 bf16
    float* hsp    = (float*)(ws + 1843840);        // 8 x 128x1024 f32 partials

    gemm_prep_kernel<<<480, 256, 0, stream>>>(feat, counts, proto, zs, W1, b1,
                                              fpT, ppbT, dotraw, zw, zwpart, invf, invp);
    hs_kernel<<<512, 256, 0, stream>>>(fpT, ppbT, W2, hsp);
    combine_kernel<<<128, 1024, 0, stream>>>(dotraw, hsp, zw, zwpart, invf, invp,
                                             temp, b2, (float*)d_out);
}